// Round 10
// baseline (11596.464 us; speedup 1.0000x reference)
//
#include <hip/hip_runtime.h>

#define B_ 64
#define T_ 512
#define D_ 32
#define U_ 512
#define SIGD 1056

typedef _Float16 half8 __attribute__((ext_vector_type(8)));
typedef float f32x4 __attribute__((ext_vector_type(4)));
typedef unsigned int u32x4 __attribute__((ext_vector_type(4)));
typedef unsigned short ushort_t;
typedef unsigned int uint_t;
typedef unsigned long long ull_t;

// ---- workspace layout (bytes) ----
#define SIG_OFF   0ull            // fp16 norm_sigs  [b*512+t][1056]           69,206,016
#define F_OFF     69206016ull     // fp16 f_all      [t][u][b]                 33,554,432
#define FLG_OFF   102760448ull    // u32 flags [t*32 + wave]                      524,288
#define A_OFF     136314880ull    // fp32 a          [b][t][i]                  4,194,304
#define DX_OFF    140509184ull    // fp32 dx         [b][t][i]                  4,194,304
#define X16_OFF   144703488ull    // fp16 x          [t][b][i]                  2,097,152
#define R16_OFF   146800640ull    // fp16 [R;Wi]     [k=544][n=1536]            1,671,168
#define WF16_OFF  148471808ull    // fp16 Wf         [k=1056][n=512]            1,081,344
#define HB_OFF    149553152ull    // fp16 h double buffer: 2 x [64][512]          131,072

// ============ K0: dx / a / x16 precompute + zero hb/flg ============
__global__ __launch_bounds__(256) void k_prep(const float* __restrict__ x,
                                              _Float16* x16, float* a_buf, float* dx_buf,
                                              uint_t* hb, uint_t* flg) {
  int b = blockIdx.x;
  int tid = threadIdx.x;
  if (b >= 64) {  // blocks 64..67: zero hb(32768 u32) + flg(131072 u32)
    for (int gi = (b - 64) * 256 + tid; gi < 163840; gi += 1024) {
      if (gi < 32768) hb[gi] = 0u;
      else flg[gi - 32768] = 0u;
    }
    return;
  }
  if (tid >= 32) return;
  int i = tid;
  float xprev = x[(b * T_) * D_ + i];
  x16[(0 * B_ + b) * D_ + i] = (_Float16)xprev;
  a_buf[(b * T_) * D_ + i] = 0.f;
  dx_buf[(b * T_) * D_ + i] = 0.f;
  float S1 = 0.f;
  for (int t = 1; t < T_; ++t) {
    float xv = x[(b * T_ + t) * D_ + i];
    float dx = xv - xprev;
    float a = S1 + 0.5f * dx;
    S1 += dx;
    a_buf[(b * T_ + t) * D_ + i] = a;
    dx_buf[(b * T_ + t) * D_ + i] = dx;
    x16[(t * B_ + b) * D_ + i] = (_Float16)xv;
    xprev = xv;
  }
}

// ============ K0b: weight fp16 conversion ============
__global__ __launch_bounds__(256) void k_weights(const float* __restrict__ rk,
                                                 const float* __restrict__ ik,
                                                 const float* __restrict__ fk,
                                                 _Float16* R16t, _Float16* Wf16) {
  int e = (blockIdx.x * 256 + threadIdx.x) * 4;
  if (e < 835584) {
    const float* src = (e < 786432) ? (rk + e) : (ik + (e - 786432));
#pragma unroll
    for (int j = 0; j < 4; ++j) R16t[e + j] = (_Float16)src[j];
  } else {
    int e2 = e - 835584;  // < 540672
#pragma unroll
    for (int j = 0; j < 4; ++j) Wf16[e2 + j] = (_Float16)fk[e2 + j];
  }
}

// ============ K1: signature stream -> normalized fp16 sig matrix ============
__global__ __launch_bounds__(1024) void k_sig(const float* __restrict__ a_buf,
                                              const float* __restrict__ dx_buf,
                                              _Float16* __restrict__ sig) {
  int b = blockIdx.x;
  int tid = threadIdx.x;
  int i = tid >> 5, j = tid & 31;
  __shared__ float a_ch[32][32];
  __shared__ float dx_ch[32][32];
  float S2 = 0.f;
  for (int t0 = 0; t0 < T_; t0 += 32) {
    a_ch[i][j]  = a_buf[(b * T_ + t0 + i) * D_ + j];
    dx_ch[i][j] = dx_buf[(b * T_ + t0 + i) * D_ + j];
    __syncthreads();
#pragma unroll 4
    for (int tt = 0; tt < 32; ++tt) {
      int t = t0 + tt;
      S2 += a_ch[tt][i] * dx_ch[tt][j];
      float inv = (t == 0) ? 0.f : (1.0f / (float)t);
      int row = b * T_ + t;
      sig[row * SIGD + 32 + i * 32 + j] = (_Float16)(S2 * inv);
      if (i == 0) {
        float s1 = a_ch[tt][j] + 0.5f * dx_ch[tt][j];
        sig[row * SIGD + j] = (_Float16)(s1 * inv);
      }
    }
    __syncthreads();
  }
}

// ============ K2: f_all = sigmoid(sig @ Wf + b_f), fp16 MFMA, out [t][u][b] ============
__global__ __launch_bounds__(256) void k_fgemm(const _Float16* __restrict__ sig,
                                               const _Float16* __restrict__ Wf16,
                                               const float* __restrict__ bias,
                                               _Float16* __restrict__ f_buf) {
  const int tid = threadIdx.x;
  const int m0 = blockIdx.x * 64;
  const int n0 = blockIdx.y * 128;
  __shared__ __align__(16) ushort_t As[64 * 40];
  __shared__ __align__(16) ushort_t Bs[128 * 40];
  const uint_t* sig32 = (const uint_t*)sig;
  const uint_t* w32 = (const uint_t*)Wf16;
  f32x4 acc[8];
#pragma unroll
  for (int nt = 0; nt < 8; ++nt) acc[nt] = f32x4{0.f, 0.f, 0.f, 0.f};
  const int lane = tid & 63, w = tid >> 6;
  const int cl = lane & 15, q8 = (lane >> 4) * 8;
  for (int kt = 0; kt < 33; ++kt) {
#pragma unroll
    for (int it = 0; it < 4; ++it) {
      int idx = tid + (it << 8);
      int row = idx >> 4, kp = idx & 15;
      uint_t v = sig32[(m0 + row) * 528 + kt * 16 + kp];
      *(uint_t*)&As[row * 40 + kp * 2] = v;
    }
#pragma unroll
    for (int it = 0; it < 8; ++it) {
      int idx = tid + (it << 8);
      int kr = idx >> 6, np = idx & 63;
      uint_t v = w32[(kt * 32 + kr) * 256 + (n0 >> 1) + np];
      Bs[(np * 2) * 40 + kr] = (ushort_t)(v & 0xffffu);
      Bs[(np * 2 + 1) * 40 + kr] = (ushort_t)(v >> 16);
    }
    __syncthreads();
    half8 a = *(const half8*)&As[(w * 16 + cl) * 40 + q8];
#pragma unroll
    for (int nt = 0; nt < 8; ++nt) {
      half8 bfr = *(const half8*)&Bs[(nt * 16 + cl) * 40 + q8];
      acc[nt] = __builtin_amdgcn_mfma_f32_16x16x32_f16(a, bfr, acc[nt], 0, 0, 0);
    }
    __syncthreads();
  }
#pragma unroll
  for (int nt = 0; nt < 8; ++nt) {
    int col = n0 + nt * 16 + cl;
    float bf = bias[512 + col];
#pragma unroll
    for (int r = 0; r < 4; ++r) {
      int m = m0 + w * 16 + ((lane >> 4) << 2) + r;
      int t = m & 511, b = m >> 9;
      float z = acc[nt][r] + bf;
      float fv = 1.f / (1.f + __expf(-z));
      f_buf[(t * 512 + col) * 64 + b] = (_Float16)fv;
    }
  }
}

// ============ K3: 8-block persistent LSTM scan (all 64 batches per block) ============
// R10: SINGLE 32-wave rendezvous instead of 8 separate ones. 8 blocks x 4
// waves; block j owns units [64j,64j+64); each wave computes its 16 units
// for ALL 64 batches (4 row-tiles of 16 -> 204 MFMAs, no duplicate rows;
// total MFMA work HALVES vs the 64-block layout). Exchange protocol is the
// R5/R8-proven chain (publish packed h -> vmcnt(0) drain -> flag -> skinny
// poll -> batched dwordx4 sc0 sc1 gather) but with 32 waves instead of 256:
// LLC ops/step drop ~10x (counted: ~20k -> ~2k). If the 2.5k-cy RTT was
// contention (queueing at 2 ops/cy), this collapses the step; if intrinsic,
// this round is ~neutral and proves the latency floor. Gather is
// double-buffered 2 row-tiles at a time so batch 2's RTT hides under
// batch 1's 102 MFMAs.
__global__ __launch_bounds__(256, 1) void k_scan(const _Float16* __restrict__ R16t,
                                                 const float* __restrict__ bias,
                                                 const _Float16* __restrict__ f16,
                                                 const _Float16* __restrict__ x16,
                                                 uint_t* hb, uint_t* flg,
                                                 float* __restrict__ out) {
  const int tid = threadIdx.x;
  const int bid = blockIdx.x;         // 0..7
  const int lane = tid & 63, w = tid >> 6;
  const int cl = lane & 15, quad = lane >> 4, q8 = quad * 8;
  const int gid = (bid << 2) | w;     // global wave id, 0..31
  const int u0 = gid * 16;            // unit tile base
  const int u = u0 + cl;              // this lane's unit

  // B fragments: 3 gates (i,c,o) x 17 ksteps = 204 VGPRs
  half8 bfr[3][17];
#pragma unroll
  for (int g3 = 0; g3 < 3; ++g3)
#pragma unroll
    for (int kk = 0; kk < 17; ++kk)
#pragma unroll
      for (int jj = 0; jj < 8; ++jj)
        bfr[g3][kk][jj] = R16t[(kk * 32 + q8 + jj) * 1536 + g3 * 512 + u];

  const float bi = bias[u];
  const float bc = bias[1024 + u];
  const float bo = bias[1536 + u];
  // cell state: 4 row-tiles x 4 rows (row = 16*rt + quad*4 + r), unit cl
  float c0[4] = {0.f,0.f,0.f,0.f}, c1[4] = {0.f,0.f,0.f,0.f};
  float c2[4] = {0.f,0.f,0.f,0.f}, c3[4] = {0.f,0.f,0.f,0.f};

#pragma unroll 1
  for (int t = 0; t < T_; ++t) {
    // ---- t-dependent, h-independent prefetch (before any waiting) ----
    ull_t fq0 = *(const ull_t*)(f16 + ((t * 512 + u) * 64 + 0  + quad * 4));
    ull_t fq1 = *(const ull_t*)(f16 + ((t * 512 + u) * 64 + 16 + quad * 4));
    ull_t fq2 = *(const ull_t*)(f16 + ((t * 512 + u) * 64 + 32 + quad * 4));
    ull_t fq3 = *(const ull_t*)(f16 + ((t * 512 + u) * 64 + 48 + quad * 4));
    half8 xa0 = *(const half8*)(x16 + ((t * 64 + 0  + cl) * 32 + q8));
    half8 xa1 = *(const half8*)(x16 + ((t * 64 + 16 + cl) * 32 + q8));
    half8 xa2 = *(const half8*)(x16 + ((t * 64 + 32 + cl) * 32 + q8));
    half8 xa3 = *(const half8*)(x16 + ((t * 64 + 48 + cl) * 32 + q8));

    // ---- accumulators (named, static idx per rule #20) ----
    f32x4 ai0{0.f,0.f,0.f,0.f}, ac0{0.f,0.f,0.f,0.f}, ao0{0.f,0.f,0.f,0.f};
    f32x4 ai1{0.f,0.f,0.f,0.f}, ac1{0.f,0.f,0.f,0.f}, ao1{0.f,0.f,0.f,0.f};
    f32x4 ai2{0.f,0.f,0.f,0.f}, ac2{0.f,0.f,0.f,0.f}, ao2{0.f,0.f,0.f,0.f};
    f32x4 ai3{0.f,0.f,0.f,0.f}, ac3{0.f,0.f,0.f,0.f}, ao3{0.f,0.f,0.f,0.f};

    // hoisted x-input MFMAs (kstep 16)
    ai0 = __builtin_amdgcn_mfma_f32_16x16x32_f16(xa0, bfr[0][16], ai0, 0, 0, 0);
    ac0 = __builtin_amdgcn_mfma_f32_16x16x32_f16(xa0, bfr[1][16], ac0, 0, 0, 0);
    ao0 = __builtin_amdgcn_mfma_f32_16x16x32_f16(xa0, bfr[2][16], ao0, 0, 0, 0);
    ai1 = __builtin_amdgcn_mfma_f32_16x16x32_f16(xa1, bfr[0][16], ai1, 0, 0, 0);
    ac1 = __builtin_amdgcn_mfma_f32_16x16x32_f16(xa1, bfr[1][16], ac1, 0, 0, 0);
    ao1 = __builtin_amdgcn_mfma_f32_16x16x32_f16(xa1, bfr[2][16], ao1, 0, 0, 0);
    ai2 = __builtin_amdgcn_mfma_f32_16x16x32_f16(xa2, bfr[0][16], ai2, 0, 0, 0);
    ac2 = __builtin_amdgcn_mfma_f32_16x16x32_f16(xa2, bfr[1][16], ac2, 0, 0, 0);
    ao2 = __builtin_amdgcn_mfma_f32_16x16x32_f16(xa2, bfr[2][16], ao2, 0, 0, 0);
    ai3 = __builtin_amdgcn_mfma_f32_16x16x32_f16(xa3, bfr[0][16], ai3, 0, 0, 0);
    ac3 = __builtin_amdgcn_mfma_f32_16x16x32_f16(xa3, bfr[1][16], ac3, 0, 0, 0);
    ao3 = __builtin_amdgcn_mfma_f32_16x16x32_f16(xa3, bfr[2][16], ao3, 0, 0, 0);

    uint_t* hb_w32 = hb + ((t & 1) ? 0 : 16384);

    if (t > 0) {
      // ---- skinny poll: 32 flags (whole machine = one rendezvous) ----
      const uint_t* fp = flg + (((t - 1)) << 5) + (lane & 31);
      int spins = 0;
      for (;;) {
        uint_t v = 1u;
        if (lane < 32)
          v = __hip_atomic_load(fp, __ATOMIC_RELAXED, __HIP_MEMORY_SCOPE_AGENT);
        if (__all(v != 0u)) break;
        if (++spins > 8) __builtin_amdgcn_s_sleep(1);
        if (spins > (1 << 17)) break;   // bail-forward: terminating, diagnosable
      }
      // ---- gather h(t-1): 4 row-tiles, double-buffered 2 at a time ----
      const char* rb = (const char*)hb + ((t & 1) ? 65536 : 0) + cl * 1024 + q8 * 2;
      u32x4 ga[16], gb[16];
      const char* ap;
#define GLD16(buf) \
      asm volatile("global_load_dwordx4 %0, %16, off offset:0 sc0 sc1\n\t" \
                   "global_load_dwordx4 %1, %16, off offset:64 sc0 sc1\n\t" \
                   "global_load_dwordx4 %2, %16, off offset:128 sc0 sc1\n\t" \
                   "global_load_dwordx4 %3, %16, off offset:192 sc0 sc1\n\t" \
                   "global_load_dwordx4 %4, %16, off offset:256 sc0 sc1\n\t" \
                   "global_load_dwordx4 %5, %16, off offset:320 sc0 sc1\n\t" \
                   "global_load_dwordx4 %6, %16, off offset:384 sc0 sc1\n\t" \
                   "global_load_dwordx4 %7, %16, off offset:448 sc0 sc1\n\t" \
                   "global_load_dwordx4 %8, %16, off offset:512 sc0 sc1\n\t" \
                   "global_load_dwordx4 %9, %16, off offset:576 sc0 sc1\n\t" \
                   "global_load_dwordx4 %10, %16, off offset:640 sc0 sc1\n\t" \
                   "global_load_dwordx4 %11, %16, off offset:704 sc0 sc1\n\t" \
                   "global_load_dwordx4 %12, %16, off offset:768 sc0 sc1\n\t" \
                   "global_load_dwordx4 %13, %16, off offset:832 sc0 sc1\n\t" \
                   "global_load_dwordx4 %14, %16, off offset:896 sc0 sc1\n\t" \
                   "global_load_dwordx4 %15, %16, off offset:960 sc0 sc1" \
                   : "=&v"(buf[0]), "=&v"(buf[1]), "=&v"(buf[2]), "=&v"(buf[3]), \
                     "=&v"(buf[4]), "=&v"(buf[5]), "=&v"(buf[6]), "=&v"(buf[7]), \
                     "=&v"(buf[8]), "=&v"(buf[9]), "=&v"(buf[10]), "=&v"(buf[11]), \
                     "=&v"(buf[12]), "=&v"(buf[13]), "=&v"(buf[14]), "=&v"(buf[15]) \
                   : "v"(ap) : "memory")
#define MFMA16(buf, AI, AC, AO) \
      _Pragma("unroll") \
      for (int kk = 0; kk < 16; ++kk) { \
        half8 af = __builtin_bit_cast(half8, buf[kk]); \
        AI = __builtin_amdgcn_mfma_f32_16x16x32_f16(af, bfr[0][kk], AI, 0, 0, 0); \
        AC = __builtin_amdgcn_mfma_f32_16x16x32_f16(af, bfr[1][kk], AC, 0, 0, 0); \
        AO = __builtin_amdgcn_mfma_f32_16x16x32_f16(af, bfr[2][kk], AO, 0, 0, 0); \
      }
      ap = rb;            GLD16(ga);   // rows 0..15
      ap = rb + 16384;    GLD16(gb);   // rows 16..31
      asm volatile("s_waitcnt vmcnt(0)" ::: "memory");
      __builtin_amdgcn_sched_barrier(0);
      MFMA16(ga, ai0, ac0, ao0)
      MFMA16(gb, ai1, ac1, ao1)
      ap = rb + 32768;    GLD16(ga);   // rows 32..47
      ap = rb + 49152;    GLD16(gb);   // rows 48..63
      asm volatile("s_waitcnt vmcnt(0)" ::: "memory");
      __builtin_amdgcn_sched_barrier(0);
      MFMA16(ga, ai2, ac2, ao2)
      MFMA16(gb, ai3, ac3, ao3)
#undef MFMA16
#undef GLD16
    }

    // ---- epilogue: 4 row-tiles -> c,h; publish packed h ----
#define EPI(RT, AI, AC, AO, CS, FQ) \
    { \
      union { ull_t q; _Float16 h[4]; } fu; fu.q = FQ; \
      _Pragma("unroll") \
      for (int r = 0; r < 4; ++r) { \
        int row = RT * 16 + quad * 4 + r; \
        float iv = 1.f / (1.f + __expf(-(AI[r] + bi))); \
        float cv = 1.f - 2.f / (__expf(2.f * (AC[r] + bc)) + 1.f); \
        float ov = 1.f / (1.f + __expf(-(AO[r] + bo))); \
        float c = (float)fu.h[r] * CS[r] + iv * cv; \
        CS[r] = c; \
        float h = ov * (1.f - 2.f / (__expf(2.f * c) + 1.f)); \
        if (t < T_ - 1) { \
          ushort_t hu = __builtin_bit_cast(ushort_t, (_Float16)h); \
          uint_t nbr = (uint_t)(unsigned)__shfl_xor((int)hu, 1); \
          uint_t packed = ((uint_t)hu & 0xffffu) | (nbr << 16); \
          if (!(cl & 1)) \
            __hip_atomic_store(&hb_w32[(row << 8) + ((u0 + cl) >> 1)], packed, \
                               __ATOMIC_RELAXED, __HIP_MEMORY_SCOPE_AGENT); \
        } else { \
          out[(row << 9) + u] = h; \
        } \
      } \
    }
    EPI(0, ai0, ac0, ao0, c0, fq0)
    EPI(1, ai1, ac1, ao1, c1, fq1)
    EPI(2, ai2, ac2, ao2, c2, fq2)
    EPI(3, ai3, ac3, ao3, c3, fq3)
#undef EPI

    // ---- drain own stores (data committed at LLC), then publish flag ----
    asm volatile("s_waitcnt vmcnt(0)" ::: "memory");
    if (lane == 0 && t < T_ - 1)
      __hip_atomic_store(&flg[(t << 5) + gid], 1u, __ATOMIC_RELAXED,
                         __HIP_MEMORY_SCOPE_AGENT);
  }
}

extern "C" void kernel_launch(void* const* d_in, const int* in_sizes, int n_in,
                              void* d_out, int out_size, void* d_ws, size_t ws_size,
                              hipStream_t stream) {
  const float* x = (const float*)d_in[0];
  const float* ik = (const float*)d_in[1];
  const float* rk = (const float*)d_in[2];
  const float* fk = (const float*)d_in[3];
  const float* bias = (const float*)d_in[4];
  char* ws = (char*)d_ws;
  _Float16* sig = (_Float16*)(ws + SIG_OFF);
  _Float16* f_buf = (_Float16*)(ws + F_OFF);
  uint_t* flg = (uint_t*)(ws + FLG_OFF);
  float* a_buf = (float*)(ws + A_OFF);
  float* dx_buf = (float*)(ws + DX_OFF);
  _Float16* x16 = (_Float16*)(ws + X16_OFF);
  _Float16* R16t = (_Float16*)(ws + R16_OFF);
  _Float16* Wf16 = (_Float16*)(ws + WF16_OFF);
  uint_t* hb = (uint_t*)(ws + HB_OFF);
  float* out = (float*)d_out;

  hipLaunchKernelGGL(k_prep, dim3(68), dim3(256), 0, stream, x, x16, a_buf, dx_buf, hb, flg);
  hipLaunchKernelGGL(k_weights, dim3(1344), dim3(256), 0, stream, rk, ik, fk, R16t, Wf16);
  hipLaunchKernelGGL(k_sig, dim3(64), dim3(1024), 0, stream, a_buf, dx_buf, sig);
  hipLaunchKernelGGL(k_fgemm, dim3(512, 4), dim3(256), 0, stream, sig, Wf16, bias, f_buf);
  hipLaunchKernelGGL(k_scan, dim3(8), dim3(256), 0, stream, R16t, bias, f_buf,
                     x16, hb, flg, out);
}

// Round 11
// 2875.020 us; speedup vs baseline: 4.0335x; 4.0335x over previous
//
#include <hip/hip_runtime.h>

#define B_ 64
#define T_ 512
#define D_ 32
#define U_ 512
#define SIGD 1056

typedef _Float16 half8 __attribute__((ext_vector_type(8)));
typedef float f32x4 __attribute__((ext_vector_type(4)));
typedef unsigned int u32x4 __attribute__((ext_vector_type(4)));
typedef unsigned short ushort_t;
typedef unsigned int uint_t;
typedef unsigned long long ull_t;

// ---- workspace layout (bytes) ----
#define SIG_OFF   0ull            // fp16 norm_sigs  [b*512+t][1056]           69,206,016
#define F_OFF     69206016ull     // fp16 f_all      [t][u][b]                 33,554,432
#define FLG_OFF   102760448ull    // u32 flags [(t*8+G)*32 + wave]                524,288
#define A_OFF     136314880ull    // fp32 a          [b][t][i]                  4,194,304
#define DX_OFF    140509184ull    // fp32 dx         [b][t][i]                  4,194,304
#define X16_OFF   144703488ull    // fp16 x          [t][b][i]                  2,097,152
#define R16_OFF   146800640ull    // fp16 [R;Wi]     [k=544][n=1536]            1,671,168
#define WF16_OFF  148471808ull    // fp16 Wf         [k=1056][n=512]            1,081,344
#define HB_OFF    149553152ull    // fp16 h double buffer: 2 x [64][512]          131,072

// ============ K0: dx / a / x16 precompute + zero hb/flg ============
__global__ __launch_bounds__(256) void k_prep(const float* __restrict__ x,
                                              _Float16* x16, float* a_buf, float* dx_buf,
                                              uint_t* hb, uint_t* flg) {
  int b = blockIdx.x;
  int tid = threadIdx.x;
  if (b >= 64) {  // blocks 64..67: zero hb(32768 u32) + flg(131072 u32)
    for (int gi = (b - 64) * 256 + tid; gi < 163840; gi += 1024) {
      if (gi < 32768) hb[gi] = 0u;
      else flg[gi - 32768] = 0u;
    }
    return;
  }
  if (tid >= 32) return;
  int i = tid;
  float xprev = x[(b * T_) * D_ + i];
  x16[(0 * B_ + b) * D_ + i] = (_Float16)xprev;
  a_buf[(b * T_) * D_ + i] = 0.f;
  dx_buf[(b * T_) * D_ + i] = 0.f;
  float S1 = 0.f;
  for (int t = 1; t < T_; ++t) {
    float xv = x[(b * T_ + t) * D_ + i];
    float dx = xv - xprev;
    float a = S1 + 0.5f * dx;
    S1 += dx;
    a_buf[(b * T_ + t) * D_ + i] = a;
    dx_buf[(b * T_ + t) * D_ + i] = dx;
    x16[(t * B_ + b) * D_ + i] = (_Float16)xv;
    xprev = xv;
  }
}

// ============ K0b: weight fp16 conversion ============
__global__ __launch_bounds__(256) void k_weights(const float* __restrict__ rk,
                                                 const float* __restrict__ ik,
                                                 const float* __restrict__ fk,
                                                 _Float16* R16t, _Float16* Wf16) {
  int e = (blockIdx.x * 256 + threadIdx.x) * 4;
  if (e < 835584) {
    const float* src = (e < 786432) ? (rk + e) : (ik + (e - 786432));
#pragma unroll
    for (int j = 0; j < 4; ++j) R16t[e + j] = (_Float16)src[j];
  } else {
    int e2 = e - 835584;  // < 540672
#pragma unroll
    for (int j = 0; j < 4; ++j) Wf16[e2 + j] = (_Float16)fk[e2 + j];
  }
}

// ============ K1: signature stream -> normalized fp16 sig matrix ============
__global__ __launch_bounds__(1024) void k_sig(const float* __restrict__ a_buf,
                                              const float* __restrict__ dx_buf,
                                              _Float16* __restrict__ sig) {
  int b = blockIdx.x;
  int tid = threadIdx.x;
  int i = tid >> 5, j = tid & 31;
  __shared__ float a_ch[32][32];
  __shared__ float dx_ch[32][32];
  float S2 = 0.f;
  for (int t0 = 0; t0 < T_; t0 += 32) {
    a_ch[i][j]  = a_buf[(b * T_ + t0 + i) * D_ + j];
    dx_ch[i][j] = dx_buf[(b * T_ + t0 + i) * D_ + j];
    __syncthreads();
#pragma unroll 4
    for (int tt = 0; tt < 32; ++tt) {
      int t = t0 + tt;
      S2 += a_ch[tt][i] * dx_ch[tt][j];
      float inv = (t == 0) ? 0.f : (1.0f / (float)t);
      int row = b * T_ + t;
      sig[row * SIGD + 32 + i * 32 + j] = (_Float16)(S2 * inv);
      if (i == 0) {
        float s1 = a_ch[tt][j] + 0.5f * dx_ch[tt][j];
        sig[row * SIGD + j] = (_Float16)(s1 * inv);
      }
    }
    __syncthreads();
  }
}

// ============ K2: f_all = sigmoid(sig @ Wf + b_f), fp16 MFMA, out [t][u][b] ============
__global__ __launch_bounds__(256) void k_fgemm(const _Float16* __restrict__ sig,
                                               const _Float16* __restrict__ Wf16,
                                               const float* __restrict__ bias,
                                               _Float16* __restrict__ f_buf) {
  const int tid = threadIdx.x;
  const int m0 = blockIdx.x * 64;
  const int n0 = blockIdx.y * 128;
  __shared__ __align__(16) ushort_t As[64 * 40];
  __shared__ __align__(16) ushort_t Bs[128 * 40];
  const uint_t* sig32 = (const uint_t*)sig;
  const uint_t* w32 = (const uint_t*)Wf16;
  f32x4 acc[8];
#pragma unroll
  for (int nt = 0; nt < 8; ++nt) acc[nt] = f32x4{0.f, 0.f, 0.f, 0.f};
  const int lane = tid & 63, w = tid >> 6;
  const int cl = lane & 15, q8 = (lane >> 4) * 8;
  for (int kt = 0; kt < 33; ++kt) {
#pragma unroll
    for (int it = 0; it < 4; ++it) {
      int idx = tid + (it << 8);
      int row = idx >> 4, kp = idx & 15;
      uint_t v = sig32[(m0 + row) * 528 + kt * 16 + kp];
      *(uint_t*)&As[row * 40 + kp * 2] = v;
    }
#pragma unroll
    for (int it = 0; it < 8; ++it) {
      int idx = tid + (it << 8);
      int kr = idx >> 6, np = idx & 63;
      uint_t v = w32[(kt * 32 + kr) * 256 + (n0 >> 1) + np];
      Bs[(np * 2) * 40 + kr] = (ushort_t)(v & 0xffffu);
      Bs[(np * 2 + 1) * 40 + kr] = (ushort_t)(v >> 16);
    }
    __syncthreads();
    half8 a = *(const half8*)&As[(w * 16 + cl) * 40 + q8];
#pragma unroll
    for (int nt = 0; nt < 8; ++nt) {
      half8 bfr = *(const half8*)&Bs[(nt * 16 + cl) * 40 + q8];
      acc[nt] = __builtin_amdgcn_mfma_f32_16x16x32_f16(a, bfr, acc[nt], 0, 0, 0);
    }
    __syncthreads();
  }
#pragma unroll
  for (int nt = 0; nt < 8; ++nt) {
    int col = n0 + nt * 16 + cl;
    float bf = bias[512 + col];
#pragma unroll
    for (int r = 0; r < 4; ++r) {
      int m = m0 + w * 16 + ((lane >> 4) << 2) + r;
      int t = m & 511, b = m >> 9;
      float z = acc[nt][r] + bf;
      float fv = 1.f / (1.f + __expf(-z));
      f_buf[(t * 512 + col) * 64 + b] = (_Float16)fv;
    }
  }
}

// ============ K3: batch-partitioned persistent LSTM scan ============
// 64 blocks = 8 groups (G = bid&7) — R5/R8 structure and protocol (publish ->
// vmcnt(0) drain -> flag -> skinny poll -> batched dwordx4 sc0 sc1 gather).
// R11 change: ONE coalesced h-store per wave instead of 64 scattered dword
// stores. The wave's 256B output (8 rows x 16 units) is redistributed
// in-register (8 shfls + selects; quads 2,3 carry valid duplicate rows so
// all 64 lanes have data) so lane L holds the dword for (row L>>3, pair
// L&7); a single all-lane store writes byte-identical data to the same
// addresses. Store instrs/step: 16k -> 256; drain acks/wave: 64 -> 1.
// R10's lesson (8-block shrink starved HBM streaming) keeps 64 blocks.
__global__ __launch_bounds__(256, 1) void k_scan(const _Float16* __restrict__ R16t,
                                                 const float* __restrict__ bias,
                                                 const _Float16* __restrict__ f16,
                                                 const _Float16* __restrict__ x16,
                                                 uint_t* hb, uint_t* flg,
                                                 float* __restrict__ out) {
  const int tid = threadIdx.x;
  const int bid = blockIdx.x;         // 0..63
  const int G = bid & 7;              // group (batch tile)
  const int mj = bid >> 3;            // member block 0..7
  const int lane = tid & 63, w = tid >> 6;
  const int cl = lane & 15, quad = lane >> 4, q8 = quad * 8;
  const int widx = (mj << 2) | w;     // producer-wave index in group, 0..31
  const int u0 = widx * 16;           // unit tile base
  const int u = u0 + cl;              // this lane's unit
  const int b0 = G * 8;               // batch base
  const int arow = b0 + (cl & 7);     // A-frag batch row (rows 8..15 duplicate)

  // coalesced-store mapping: lane holds dword (row lane>>3, unit-pair lane&7)
  const int srcl = ((lane >> 5) & 1) * 16 + (lane & 7) * 2;  // source lane (quad 0/1)
  const int rsel = (lane >> 3) & 3;                          // source r-index

  // B fragments: 3 gates (i,c,o) x 17 ksteps = 204 VGPRs
  half8 bfr[3][17];
#pragma unroll
  for (int g3 = 0; g3 < 3; ++g3)
#pragma unroll
    for (int kk = 0; kk < 17; ++kk)
#pragma unroll
      for (int jj = 0; jj < 8; ++jj)
        bfr[g3][kk][jj] = R16t[(kk * 32 + q8 + jj) * 1536 + g3 * 512 + u];

  const float bi = bias[u];
  const float bc = bias[1024 + u];
  const float bo = bias[1536 + u];
  float c_st[4] = {0.f, 0.f, 0.f, 0.f};

#pragma unroll 1
  for (int t = 0; t < T_; ++t) {
    // ---- t-dependent, h-independent prefetch (before any waiting) ----
    float fpre[4];
    {
      union { ull_t q; _Float16 h[4]; } fu;
      fu.q = *(const ull_t*)(f16 + ((t * 512 + u) * 64 + b0 + (quad & 1) * 4));
#pragma unroll
      for (int r = 0; r < 4; ++r) fpre[r] = (float)fu.h[r];
    }
    half8 xa = *(const half8*)(x16 + ((t * 64 + arow) * 32 + q8));

    // ---- hoisted x-input MFMAs (kstep 16): no h dependence ----
    f32x4 ai = f32x4{0.f, 0.f, 0.f, 0.f};
    f32x4 ac = f32x4{0.f, 0.f, 0.f, 0.f};
    f32x4 ao = f32x4{0.f, 0.f, 0.f, 0.f};
    ai = __builtin_amdgcn_mfma_f32_16x16x32_f16(xa, bfr[0][16], ai, 0, 0, 0);
    ac = __builtin_amdgcn_mfma_f32_16x16x32_f16(xa, bfr[1][16], ac, 0, 0, 0);
    ao = __builtin_amdgcn_mfma_f32_16x16x32_f16(xa, bfr[2][16], ao, 0, 0, 0);

    uint_t* hb_w32 = hb + ((t & 1) ? 0 : 16384);

    if (t > 0) {
      // ---- skinny flag poll (tight-spin first 4, then sleepy) ----
      const uint_t* fp = flg + (((t - 1) * 8 + G) << 5) + (lane & 31);
      int spins = 0;
      for (;;) {
        uint_t v = 1u;
        if (lane < 32)
          v = __hip_atomic_load(fp, __ATOMIC_RELAXED, __HIP_MEMORY_SCOPE_AGENT);
        if (__all(v != 0u)) break;
        if (++spins > 4) __builtin_amdgcn_s_sleep(1);
        if (spins > (1 << 18)) break;   // bail-forward (R4 discipline)
      }
      // ---- batched gather: 16 x dwordx4, one waitcnt (R5-proven) ----
      half8 ga[16];
      const char* hb_r = (const char*)hb + ((t & 1) ? 65536 : 0) + arow * 1024 + q8 * 2;
#define GLD(i, off) \
      asm volatile("global_load_dwordx4 %0, %1, off offset:" #off " sc0 sc1" \
                   : "=&v"(ga[i]) : "v"(hb_r))
      GLD(0, 0);    GLD(1, 64);   GLD(2, 128);  GLD(3, 192);
      GLD(4, 256);  GLD(5, 320);  GLD(6, 384);  GLD(7, 448);
      GLD(8, 512);  GLD(9, 576);  GLD(10, 640); GLD(11, 704);
      GLD(12, 768); GLD(13, 832); GLD(14, 896); GLD(15, 960);
#undef GLD
      asm volatile("s_waitcnt vmcnt(0)" ::: "memory");
      __builtin_amdgcn_sched_barrier(0);
      // ---- 48 h-MFMAs ----
#pragma unroll
      for (int kk = 0; kk < 16; ++kk) {
        ai = __builtin_amdgcn_mfma_f32_16x16x32_f16(ga[kk], bfr[0][kk], ai, 0, 0, 0);
        ac = __builtin_amdgcn_mfma_f32_16x16x32_f16(ga[kk], bfr[1][kk], ac, 0, 0, 0);
        ao = __builtin_amdgcn_mfma_f32_16x16x32_f16(ga[kk], bfr[2][kk], ao, 0, 0, 0);
      }
    }

    // ---- epilogue: gates -> c,h (all 64 lanes valid; quads 2,3 = dup rows) ----
    ushort_t hu0, hu1, hu2, hu3;
#define EPI_R(r, HU) { \
      float iv = 1.f / (1.f + __expf(-(ai[r] + bi))); \
      float cv = 1.f - 2.f / (__expf(2.f * (ac[r] + bc)) + 1.f); \
      float ov = 1.f / (1.f + __expf(-(ao[r] + bo))); \
      float c = fpre[r] * c_st[r] + iv * cv; \
      c_st[r] = c; \
      float h = ov * (1.f - 2.f / (__expf(2.f * c) + 1.f)); \
      HU = __builtin_bit_cast(ushort_t, (_Float16)h); \
      if (t == T_ - 1) { \
        int brow = (quad << 2) + r; \
        if (brow < 8) out[((b0 + brow) << 9) + u] = h; \
      } \
    }
    EPI_R(0, hu0) EPI_R(1, hu1) EPI_R(2, hu2) EPI_R(3, hu3)
#undef EPI_R

    if (t < T_ - 1) {
      // ---- in-register transpose -> ONE coalesced store per wave ----
      // lane L takes units (u0+2*(L&7), +1) of row (L>>3) from source lane
      // srcl=(L>>5)*16+(L&7)*2 at r-index rsel=(L>>3)&3.
      uint_t d0 = ((uint_t)(ushort_t)__shfl((int)hu0, srcl) & 0xffffu) |
                  ((uint_t)(ushort_t)__shfl((int)hu0, srcl + 1) << 16);
      uint_t d1 = ((uint_t)(ushort_t)__shfl((int)hu1, srcl) & 0xffffu) |
                  ((uint_t)(ushort_t)__shfl((int)hu1, srcl + 1) << 16);
      uint_t d2 = ((uint_t)(ushort_t)__shfl((int)hu2, srcl) & 0xffffu) |
                  ((uint_t)(ushort_t)__shfl((int)hu2, srcl + 1) << 16);
      uint_t d3 = ((uint_t)(ushort_t)__shfl((int)hu3, srcl) & 0xffffu) |
                  ((uint_t)(ushort_t)__shfl((int)hu3, srcl + 1) << 16);
      uint_t dd = (rsel == 0) ? d0 : (rsel == 1) ? d1 : (rsel == 2) ? d2 : d3;
      int row = b0 + (lane >> 3);                      // global batch row
      uint_t* p = hb_w32 + row * 256 + (u0 >> 1) + (lane & 7);
      __hip_atomic_store(p, dd, __ATOMIC_RELAXED, __HIP_MEMORY_SCOPE_AGENT);
      // ---- drain (1 ack) + publish flag ----
      asm volatile("s_waitcnt vmcnt(0)" ::: "memory");
      if (lane == 0)
        __hip_atomic_store(&flg[((t * 8 + G) << 5) + widx], 1u, __ATOMIC_RELAXED,
                           __HIP_MEMORY_SCOPE_AGENT);
    }
  }
}

extern "C" void kernel_launch(void* const* d_in, const int* in_sizes, int n_in,
                              void* d_out, int out_size, void* d_ws, size_t ws_size,
                              hipStream_t stream) {
  const float* x = (const float*)d_in[0];
  const float* ik = (const float*)d_in[1];
  const float* rk = (const float*)d_in[2];
  const float* fk = (const float*)d_in[3];
  const float* bias = (const float*)d_in[4];
  char* ws = (char*)d_ws;
  _Float16* sig = (_Float16*)(ws + SIG_OFF);
  _Float16* f_buf = (_Float16*)(ws + F_OFF);
  uint_t* flg = (uint_t*)(ws + FLG_OFF);
  float* a_buf = (float*)(ws + A_OFF);
  float* dx_buf = (float*)(ws + DX_OFF);
  _Float16* x16 = (_Float16*)(ws + X16_OFF);
  _Float16* R16t = (_Float16*)(ws + R16_OFF);
  _Float16* Wf16 = (_Float16*)(ws + WF16_OFF);
  uint_t* hb = (uint_t*)(ws + HB_OFF);
  float* out = (float*)d_out;

  hipLaunchKernelGGL(k_prep, dim3(68), dim3(256), 0, stream, x, x16, a_buf, dx_buf, hb, flg);
  hipLaunchKernelGGL(k_weights, dim3(1344), dim3(256), 0, stream, rk, ik, fk, R16t, Wf16);
  hipLaunchKernelGGL(k_sig, dim3(64), dim3(1024), 0, stream, a_buf, dx_buf, sig);
  hipLaunchKernelGGL(k_fgemm, dim3(512, 4), dim3(256), 0, stream, sig, Wf16, bias, f_buf);
  hipLaunchKernelGGL(k_scan, dim3(64), dim3(256), 0, stream, R16t, bias, f_buf,
                     x16, hb, flg, out);
}

// Round 13
// 1875.406 us; speedup vs baseline: 6.1834x; 1.5330x over previous
//
#include <hip/hip_runtime.h>

#define B_ 64
#define T_ 512
#define D_ 32
#define U_ 512
#define SIGD 1056

typedef _Float16 half8 __attribute__((ext_vector_type(8)));
typedef float f32x4 __attribute__((ext_vector_type(4)));
typedef unsigned int u32x4 __attribute__((ext_vector_type(4)));
typedef unsigned short ushort_t;
typedef unsigned int uint_t;
typedef unsigned long long ull_t;

// ---- workspace layout (bytes) ----
#define SIG_OFF   0ull            // fp16 norm_sigs  [b*512+t][1056]           69,206,016
#define F_OFF     69206016ull     // fp16 f_all      [t][u][b]                 33,554,432
#define FLG_OFF   102760448ull    // u32 counters: ctr[G] at dword G*64           524,288
#define A_OFF     136314880ull    // fp32 a          [b][t][i]                  4,194,304
#define DX_OFF    140509184ull    // fp32 dx         [b][t][i]                  4,194,304
#define X16_OFF   144703488ull    // fp16 x          [t][b][i]                  2,097,152
#define R16_OFF   146800640ull    // fp16 [R;Wi]     [k=544][n=1536]            1,671,168
#define WF16_OFF  148471808ull    // fp16 Wf         [k=1056][n=512]            1,081,344
#define HB_OFF    149553152ull    // fp16 h double buffer: 2 x [64][512]          131,072

// ============ K0: dx / a / x16 precompute + zero hb/flg ============
__global__ __launch_bounds__(256) void k_prep(const float* __restrict__ x,
                                              _Float16* x16, float* a_buf, float* dx_buf,
                                              uint_t* hb, uint_t* flg) {
  int b = blockIdx.x;
  int tid = threadIdx.x;
  if (b >= 64) {  // blocks 64..67: zero hb(32768 u32) + flg(131072 u32)
    for (int gi = (b - 64) * 256 + tid; gi < 163840; gi += 1024) {
      if (gi < 32768) hb[gi] = 0u;
      else flg[gi - 32768] = 0u;
    }
    return;
  }
  if (tid >= 32) return;
  int i = tid;
  float xprev = x[(b * T_) * D_ + i];
  x16[(0 * B_ + b) * D_ + i] = (_Float16)xprev;
  a_buf[(b * T_) * D_ + i] = 0.f;
  dx_buf[(b * T_) * D_ + i] = 0.f;
  float S1 = 0.f;
  for (int t = 1; t < T_; ++t) {
    float xv = x[(b * T_ + t) * D_ + i];
    float dx = xv - xprev;
    float a = S1 + 0.5f * dx;
    S1 += dx;
    a_buf[(b * T_ + t) * D_ + i] = a;
    dx_buf[(b * T_ + t) * D_ + i] = dx;
    x16[(t * B_ + b) * D_ + i] = (_Float16)xv;
    xprev = xv;
  }
}

// ============ K0b: weight fp16 conversion ============
__global__ __launch_bounds__(256) void k_weights(const float* __restrict__ rk,
                                                 const float* __restrict__ ik,
                                                 const float* __restrict__ fk,
                                                 _Float16* R16t, _Float16* Wf16) {
  int e = (blockIdx.x * 256 + threadIdx.x) * 4;
  if (e < 835584) {
    const float* src = (e < 786432) ? (rk + e) : (ik + (e - 786432));
#pragma unroll
    for (int j = 0; j < 4; ++j) R16t[e + j] = (_Float16)src[j];
  } else {
    int e2 = e - 835584;  // < 540672
#pragma unroll
    for (int j = 0; j < 4; ++j) Wf16[e2 + j] = (_Float16)fk[e2 + j];
  }
}

// ============ K1: signature stream -> normalized fp16 sig matrix ============
__global__ __launch_bounds__(1024) void k_sig(const float* __restrict__ a_buf,
                                              const float* __restrict__ dx_buf,
                                              _Float16* __restrict__ sig) {
  int b = blockIdx.x;
  int tid = threadIdx.x;
  int i = tid >> 5, j = tid & 31;
  __shared__ float a_ch[32][32];
  __shared__ float dx_ch[32][32];
  float S2 = 0.f;
  for (int t0 = 0; t0 < T_; t0 += 32) {
    a_ch[i][j]  = a_buf[(b * T_ + t0 + i) * D_ + j];
    dx_ch[i][j] = dx_buf[(b * T_ + t0 + i) * D_ + j];
    __syncthreads();
#pragma unroll 4
    for (int tt = 0; tt < 32; ++tt) {
      int t = t0 + tt;
      S2 += a_ch[tt][i] * dx_ch[tt][j];
      float inv = (t == 0) ? 0.f : (1.0f / (float)t);
      int row = b * T_ + t;
      sig[row * SIGD + 32 + i * 32 + j] = (_Float16)(S2 * inv);
      if (i == 0) {
        float s1 = a_ch[tt][j] + 0.5f * dx_ch[tt][j];
        sig[row * SIGD + j] = (_Float16)(s1 * inv);
      }
    }
    __syncthreads();
  }
}

// ============ K2: f_all = sigmoid(sig @ Wf + b_f), fp16 MFMA, out [t][u][b] ============
__global__ __launch_bounds__(256) void k_fgemm(const _Float16* __restrict__ sig,
                                               const _Float16* __restrict__ Wf16,
                                               const float* __restrict__ bias,
                                               _Float16* __restrict__ f_buf) {
  const int tid = threadIdx.x;
  const int m0 = blockIdx.x * 64;
  const int n0 = blockIdx.y * 128;
  __shared__ __align__(16) ushort_t As[64 * 40];
  __shared__ __align__(16) ushort_t Bs[128 * 40];
  const uint_t* sig32 = (const uint_t*)sig;
  const uint_t* w32 = (const uint_t*)Wf16;
  f32x4 acc[8];
#pragma unroll
  for (int nt = 0; nt < 8; ++nt) acc[nt] = f32x4{0.f, 0.f, 0.f, 0.f};
  const int lane = tid & 63, w = tid >> 6;
  const int cl = lane & 15, q8 = (lane >> 4) * 8;
  for (int kt = 0; kt < 33; ++kt) {
#pragma unroll
    for (int it = 0; it < 4; ++it) {
      int idx = tid + (it << 8);
      int row = idx >> 4, kp = idx & 15;
      uint_t v = sig32[(m0 + row) * 528 + kt * 16 + kp];
      *(uint_t*)&As[row * 40 + kp * 2] = v;
    }
#pragma unroll
    for (int it = 0; it < 8; ++it) {
      int idx = tid + (it << 8);
      int kr = idx >> 6, np = idx & 63;
      uint_t v = w32[(kt * 32 + kr) * 256 + (n0 >> 1) + np];
      Bs[(np * 2) * 40 + kr] = (ushort_t)(v & 0xffffu);
      Bs[(np * 2 + 1) * 40 + kr] = (ushort_t)(v >> 16);
    }
    __syncthreads();
    half8 a = *(const half8*)&As[(w * 16 + cl) * 40 + q8];
#pragma unroll
    for (int nt = 0; nt < 8; ++nt) {
      half8 bfr = *(const half8*)&Bs[(nt * 16 + cl) * 40 + q8];
      acc[nt] = __builtin_amdgcn_mfma_f32_16x16x32_f16(a, bfr, acc[nt], 0, 0, 0);
    }
    __syncthreads();
  }
#pragma unroll
  for (int nt = 0; nt < 8; ++nt) {
    int col = n0 + nt * 16 + cl;
    float bf = bias[512 + col];
#pragma unroll
    for (int r = 0; r < 4; ++r) {
      int m = m0 + w * 16 + ((lane >> 4) << 2) + r;
      int t = m & 511, b = m >> 9;
      float z = acc[nt][r] + bf;
      float fv = 1.f / (1.f + __expf(-z));
      f_buf[(t * 512 + col) * 64 + b] = (_Float16)fv;
    }
  }
}

// ============ K3: batch-partitioned persistent LSTM scan ============
// 64 blocks = 8 groups (G = bid&7). R12/R13: kill gather amplification.
// Before: each of 32 consumer waves per group loaded 16KB of per-lane
// fragments from the SAME 8KB h-slab (512KB, ~32k scattered 16B LLC requests
// per group-step). Now: each BLOCK cooperatively loads the 8KB slab ONCE
// (coalesced, 256 threads x 2 dwordx4 -> full-line transactions) into a
// double-buffered LDS slab (row pad +16B), barrier, waves ds_read_b128
// their fragments (byte-identical content). Group-step reads: 512KB -> 64KB.
// Flags replaced by ONE counter/group: producers atomicAdd(1) after drain;
// consumers poll a single wave-uniform dword (1 req/wave/iter vs 32).
// Dbuf + per-step barrier prevent LDS overwrite races. Producer protocol
// otherwise = R11 (coalesced 256B store/wave -> vmcnt(0) drain -> publish).
// R13 fix: offset:4096 > 13-bit imm range -> second load gets its own
// address operand with offset:0.
__global__ __launch_bounds__(256, 1) void k_scan(const _Float16* __restrict__ R16t,
                                                 const float* __restrict__ bias,
                                                 const _Float16* __restrict__ f16,
                                                 const _Float16* __restrict__ x16,
                                                 uint_t* hb, uint_t* flg,
                                                 float* __restrict__ out) {
  const int tid = threadIdx.x;
  const int bid = blockIdx.x;         // 0..63
  const int G = bid & 7;              // group (batch tile)
  const int mj = bid >> 3;            // member block 0..7
  const int lane = tid & 63, w = tid >> 6;
  const int cl = lane & 15, quad = lane >> 4, q8 = quad * 8;
  const int widx = (mj << 2) | w;     // producer-wave index in group, 0..31
  const int u0 = widx * 16;           // unit tile base
  const int u = u0 + cl;              // this lane's unit
  const int b0 = G * 8;               // batch base

  // coalesced-store mapping (R11): lane holds dword (row lane>>3, pair lane&7)
  const int srcl = ((lane >> 5) & 1) * 16 + (lane & 7) * 2;
  const int rsel = (lane >> 3) & 3;

  // LDS h slab: 2 buffers x 8 rows x 1040B (1024 data + 16 pad)
  __shared__ __align__(16) char hlds[2][8 * 1040];

  // B fragments: 3 gates (i,c,o) x 17 ksteps = 204 VGPRs
  half8 bfr[3][17];
#pragma unroll
  for (int g3 = 0; g3 < 3; ++g3)
#pragma unroll
    for (int kk = 0; kk < 17; ++kk)
#pragma unroll
      for (int jj = 0; jj < 8; ++jj)
        bfr[g3][kk][jj] = R16t[(kk * 32 + q8 + jj) * 1536 + g3 * 512 + u];

  const float bi = bias[u];
  const float bc = bias[1024 + u];
  const float bo = bias[1536 + u];
  float c_st[4] = {0.f, 0.f, 0.f, 0.f};

#pragma unroll 1
  for (int t = 0; t < T_; ++t) {
    // ---- t-dependent, h-independent prefetch (before any waiting) ----
    float fpre[4];
    {
      union { ull_t q; _Float16 h[4]; } fu;
      fu.q = *(const ull_t*)(f16 + ((t * 512 + u) * 64 + b0 + (quad & 1) * 4));
#pragma unroll
      for (int r = 0; r < 4; ++r) fpre[r] = (float)fu.h[r];
    }
    half8 xa = *(const half8*)(x16 + ((t * 64 + b0 + (cl & 7)) * 32 + q8));

    // ---- hoisted x-input MFMAs (kstep 16): no h dependence ----
    f32x4 ai = f32x4{0.f, 0.f, 0.f, 0.f};
    f32x4 ac = f32x4{0.f, 0.f, 0.f, 0.f};
    f32x4 ao = f32x4{0.f, 0.f, 0.f, 0.f};
    ai = __builtin_amdgcn_mfma_f32_16x16x32_f16(xa, bfr[0][16], ai, 0, 0, 0);
    ac = __builtin_amdgcn_mfma_f32_16x16x32_f16(xa, bfr[1][16], ac, 0, 0, 0);
    ao = __builtin_amdgcn_mfma_f32_16x16x32_f16(xa, bfr[2][16], ao, 0, 0, 0);

    uint_t* hb_w32 = hb + ((t & 1) ? 0 : 16384);

    if (t > 0) {
      // ---- poll group counter: producers of steps 0..t-1 added 32*t ----
      const uint_t target = 32u * (uint_t)t;
      const uint_t* cp = flg + (G << 6);   // wave-uniform address -> 1 req/iter
      int spins = 0;
      for (;;) {
        uint_t v = __hip_atomic_load(cp, __ATOMIC_RELAXED, __HIP_MEMORY_SCOPE_AGENT);
        if (v >= target) break;
        if (++spins > 16) __builtin_amdgcn_s_sleep(1);
        if (spins > (1 << 18)) break;      // bail-forward (R4 discipline)
      }
      // ---- cooperative stage: 8KB slab (rows b0..b0+7) -> LDS, coalesced ----
      {
        const char* src = (const char*)hb + ((t & 1) ? 65536 : 0)
                        + (unsigned)b0 * 1024 + (unsigned)tid * 16;
        const char* src2 = src + 4096;   // 13-bit imm limit: own addr, offset:0
        u32x4 s0, s1;
        asm volatile("global_load_dwordx4 %0, %2, off sc0 sc1\n\t"
                     "global_load_dwordx4 %1, %3, off sc0 sc1"
                     : "=&v"(s0), "=&v"(s1) : "v"(src), "v"(src2) : "memory");
        asm volatile("s_waitcnt vmcnt(0)" ::: "memory");
        __builtin_amdgcn_sched_barrier(0);
        int r0 = tid >> 6, cb = (tid & 63) * 16;
        char* dst = &hlds[t & 1][0];
        *(u32x4*)(dst + r0 * 1040 + cb) = s0;
        *(u32x4*)(dst + (r0 + 4) * 1040 + cb) = s1;
      }
      __syncthreads();
      // ---- 48 h-MFMAs, fragments from LDS (byte-identical to old gather) ----
      const char* lbase = &hlds[t & 1][(cl & 7) * 1040 + quad * 16];
#pragma unroll
      for (int kk = 0; kk < 16; ++kk) {
        half8 af = *(const half8*)(lbase + kk * 64);
        ai = __builtin_amdgcn_mfma_f32_16x16x32_f16(af, bfr[0][kk], ai, 0, 0, 0);
        ac = __builtin_amdgcn_mfma_f32_16x16x32_f16(af, bfr[1][kk], ac, 0, 0, 0);
        ao = __builtin_amdgcn_mfma_f32_16x16x32_f16(af, bfr[2][kk], ao, 0, 0, 0);
      }
    }

    // ---- epilogue: gates -> c,h (all 64 lanes valid; quads 2,3 = dup rows) ----
    ushort_t hu0, hu1, hu2, hu3;
#define EPI_R(r, HU) { \
      float iv = 1.f / (1.f + __expf(-(ai[r] + bi))); \
      float cv = 1.f - 2.f / (__expf(2.f * (ac[r] + bc)) + 1.f); \
      float ov = 1.f / (1.f + __expf(-(ao[r] + bo))); \
      float c = fpre[r] * c_st[r] + iv * cv; \
      c_st[r] = c; \
      float h = ov * (1.f - 2.f / (__expf(2.f * c) + 1.f)); \
      HU = __builtin_bit_cast(ushort_t, (_Float16)h); \
      if (t == T_ - 1) { \
        int brow = (quad << 2) + r; \
        if (brow < 8) out[((b0 + brow) << 9) + u] = h; \
      } \
    }
    EPI_R(0, hu0) EPI_R(1, hu1) EPI_R(2, hu2) EPI_R(3, hu3)
#undef EPI_R

    if (t < T_ - 1) {
      // ---- in-register transpose -> ONE coalesced store per wave (R11) ----
      uint_t d0 = ((uint_t)(ushort_t)__shfl((int)hu0, srcl) & 0xffffu) |
                  ((uint_t)(ushort_t)__shfl((int)hu0, srcl + 1) << 16);
      uint_t d1 = ((uint_t)(ushort_t)__shfl((int)hu1, srcl) & 0xffffu) |
                  ((uint_t)(ushort_t)__shfl((int)hu1, srcl + 1) << 16);
      uint_t d2 = ((uint_t)(ushort_t)__shfl((int)hu2, srcl) & 0xffffu) |
                  ((uint_t)(ushort_t)__shfl((int)hu2, srcl + 1) << 16);
      uint_t d3 = ((uint_t)(ushort_t)__shfl((int)hu3, srcl) & 0xffffu) |
                  ((uint_t)(ushort_t)__shfl((int)hu3, srcl + 1) << 16);
      uint_t dd = (rsel == 0) ? d0 : (rsel == 1) ? d1 : (rsel == 2) ? d2 : d3;
      int row = b0 + (lane >> 3);                      // global batch row
      uint_t* p = hb_w32 + row * 256 + (u0 >> 1) + (lane & 7);
      __hip_atomic_store(p, dd, __ATOMIC_RELAXED, __HIP_MEMORY_SCOPE_AGENT);
      // ---- drain (1 ack), then publish: counter += 1 ----
      asm volatile("s_waitcnt vmcnt(0)" ::: "memory");
      if (lane == 0)
        __hip_atomic_fetch_add(flg + (G << 6), 1u, __ATOMIC_RELAXED,
                               __HIP_MEMORY_SCOPE_AGENT);
    }
  }
}

extern "C" void kernel_launch(void* const* d_in, const int* in_sizes, int n_in,
                              void* d_out, int out_size, void* d_ws, size_t ws_size,
                              hipStream_t stream) {
  const float* x = (const float*)d_in[0];
  const float* ik = (const float*)d_in[1];
  const float* rk = (const float*)d_in[2];
  const float* fk = (const float*)d_in[3];
  const float* bias = (const float*)d_in[4];
  char* ws = (char*)d_ws;
  _Float16* sig = (_Float16*)(ws + SIG_OFF);
  _Float16* f_buf = (_Float16*)(ws + F_OFF);
  uint_t* flg = (uint_t*)(ws + FLG_OFF);
  float* a_buf = (float*)(ws + A_OFF);
  float* dx_buf = (float*)(ws + DX_OFF);
  _Float16* x16 = (_Float16*)(ws + X16_OFF);
  _Float16* R16t = (_Float16*)(ws + R16_OFF);
  _Float16* Wf16 = (_Float16*)(ws + WF16_OFF);
  uint_t* hb = (uint_t*)(ws + HB_OFF);
  float* out = (float*)d_out;

  hipLaunchKernelGGL(k_prep, dim3(68), dim3(256), 0, stream, x, x16, a_buf, dx_buf, hb, flg);
  hipLaunchKernelGGL(k_weights, dim3(1344), dim3(256), 0, stream, rk, ik, fk, R16t, Wf16);
  hipLaunchKernelGGL(k_sig, dim3(64), dim3(1024), 0, stream, a_buf, dx_buf, sig);
  hipLaunchKernelGGL(k_fgemm, dim3(512, 4), dim3(256), 0, stream, sig, Wf16, bias, f_buf);
  hipLaunchKernelGGL(k_scan, dim3(64), dim3(256), 0, stream, R16t, bias, f_buf,
                     x16, hb, flg, out);
}